// Round 3
// baseline (86.217 us; speedup 1.0000x reference)
//
#include <hip/hip_runtime.h>
#include <hip/hip_bf16.h>

#define N_DIM 64
#define C_DIM 16
#define J_DIM 25
#define T_DIM 120
#define O_DIM 64
#define SIG   306
#define KW    320        // ys/Wf row stride in bf16 elems; 640 B rows, XOR-swizzled
#define KITER 10         // 10*32 = 320 k

typedef __attribute__((ext_vector_type(8))) short bf16x8;
typedef __attribute__((ext_vector_type(4))) float f32x4;

__device__ __forceinline__ unsigned short f2bf(float f) {
    __hip_bfloat16 h = __float2bfloat16(f);
    return __builtin_bit_cast(unsigned short, h);
}

// ---- kernel 1: W (306x64 f32) -> Wf[o][k] bf16, k padded to 320 with zeros ----
__global__ void wprep(const float* __restrict__ W, unsigned short* __restrict__ Wf) {
    int i = blockIdx.x * 256 + threadIdx.x;       // 64 * 40 groups of 8 k
    if (i >= O_DIM * (KW / 8)) return;
    int o = i / (KW / 8);
    int k0 = (i % (KW / 8)) * 8;
    unsigned short v[8];
    #pragma unroll
    for (int u = 0; u < 8; ++u) {
        int k = k0 + u;
        v[u] = f2bf((k < SIG) ? W[k * O_DIM + o] : 0.0f);
    }
    *(uint4*)(Wf + o * KW + k0) = *(uint4*)v;
}

// ---- kernel 2: barrier-free; each wave owns one (n, j, 16-row t-tile) ----
__global__ __launch_bounds__(256, 4) void sig_mfma(
    const float* __restrict__ x, const unsigned short* __restrict__ Wf,
    const float* __restrict__ bias, float* __restrict__ out)
{
    __shared__ unsigned short ys[4][16 * KW];     // 40,960 B total -> 4 blocks/CU

    const int tid = threadIdx.x;
    const int wave = tid >> 6;
    const int lane = tid & 63;
    const int tl = lane & 15;                     // t-row within tile
    const int q  = lane >> 4;                     // work split / k-subgroup
    const int bid = blockIdx.x;
    const int half = bid & 1;
    const int j = (bid >> 1) % J_DIM;
    const int n = bid / (2 * J_DIM);
    const int tt = half * 4 + wave;               // tile 0..7
    const int t0 = (tt < 7) ? tt * 16 : 104;      // last tile overlaps (identical rows)

    unsigned short* Y = &ys[wave][0];
    char* Yrow = (char*)Y + tl * (KW * 2);
    const int swz = (tl & 7) << 4;                // byte-XOR swizzle key for this row

    // zero the k = 306..319 pad of row tl (4 q-groups split 14 elems; dups benign)
    #pragma unroll
    for (int u = 0; u < 4; ++u) {
        int f = 306 + q * 4 + u;
        if (f < KW) *(unsigned short*)(Yrow + ((f * 2) ^ swz)) = 0;
    }

    // ---- phase 1: signature features for row tl ----
    {
        const int t = t0 + tl;
        const int start = max(t - 2, 0);
        const int end   = min(t + 3, T_DIM);
        const float invLm1 = 1.0f / (float)(end - start - 1);
        int pc[5]; float pt[5];
        #pragma unroll
        for (int w = 0; w < 5; ++w) {
            int p = t - 2 + w;
            pc[w] = min(max(p, 0), T_DIM - 1);
            pt[w] = (float)(pc[w] - start) * invLm1;
        }
        const float* xb = x + (size_t)n * C_DIM * J_DIM * T_DIM + j * T_DIM;

        // midpoint rows a = q + 4i (i=0..3); q==0 also handles time row a=16
        float m[4][5];
        #pragma unroll
        for (int i = 0; i < 4; ++i) {
            const int a = q + 4 * i;
            float pa[5];
            #pragma unroll
            for (int w = 0; w < 5; ++w) pa[w] = xb[a * (J_DIM * T_DIM) + pc[w]];
            m[i][0] = 0.5f * pa[0];
            #pragma unroll
            for (int w = 1; w < 5; ++w) m[i][w] = 0.5f * (pa[w - 1] + pa[w]);
            *(unsigned short*)(Yrow + ((a * 2) ^ swz)) = f2bf(pa[4]);   // S1
        }
        float mt[5];
        if (q == 0) {
            mt[0] = 0.5f * pt[0];
            #pragma unroll
            for (int w = 1; w < 5; ++w) mt[w] = 0.5f * (pt[w - 1] + pt[w]);
            *(unsigned short*)(Yrow + ((16 * 2) ^ swz)) = f2bf(pt[4]);
        }

        #pragma unroll 4
        for (int b = 0; b < 16; ++b) {
            float pb[5], dv[5];
            #pragma unroll
            for (int w = 0; w < 5; ++w) pb[w] = xb[b * (J_DIM * T_DIM) + pc[w]];
            dv[0] = pb[0];
            #pragma unroll
            for (int w = 1; w < 5; ++w) dv[w] = pb[w] - pb[w - 1];
            #pragma unroll
            for (int i = 0; i < 4; ++i) {
                float acc = 0.0f;
                #pragma unroll
                for (int w = 0; w < 5; ++w) acc = fmaf(m[i][w], dv[w], acc);
                int f = 17 + (q + 4 * i) * 17 + b;
                *(unsigned short*)(Yrow + ((f * 2) ^ swz)) = f2bf(acc);
            }
            if (q == 0) {
                float acc = 0.0f;
                #pragma unroll
                for (int w = 0; w < 5; ++w) acc = fmaf(mt[w], dv[w], acc);
                int f = 17 + 16 * 17 + b;
                *(unsigned short*)(Yrow + ((f * 2) ^ swz)) = f2bf(acc);
            }
        }
        {   // b = 16 : time column
            float dv[5];
            dv[0] = pt[0];
            #pragma unroll
            for (int w = 1; w < 5; ++w) dv[w] = pt[w] - pt[w - 1];
            #pragma unroll
            for (int i = 0; i < 4; ++i) {
                float acc = 0.0f;
                #pragma unroll
                for (int w = 0; w < 5; ++w) acc = fmaf(m[i][w], dv[w], acc);
                int f = 17 + (q + 4 * i) * 17 + 16;
                *(unsigned short*)(Yrow + ((f * 2) ^ swz)) = f2bf(acc);
            }
            if (q == 0) {
                float acc = 0.0f;
                #pragma unroll
                for (int w = 0; w < 5; ++w) acc = fmaf(mt[w], dv[w], acc);
                int f = 17 + 16 * 17 + 16;
                *(unsigned short*)(Yrow + ((f * 2) ^ swz)) = f2bf(acc);
            }
        }
    }

    __builtin_amdgcn_wave_barrier();   // pin phase order within wave (no s_barrier)

    // ---- phase 2: this wave's (16 x 320) @ Wf^T (320 x 64) ----
    {
        const int l15 = tl;
        const int l4  = q;
        f32x4 acc[4];
        #pragma unroll
        for (int c = 0; c < 4; ++c) {
            float bv = bias[c * 16 + l15];
            acc[c] = f32x4{bv, bv, bv, bv};
        }
        const char* Ab = (char*)Y + l15 * (KW * 2);
        const int aswz = (l15 & 7) << 4;
        const unsigned short* Bb = Wf + l15 * KW + l4 * 8;
        #pragma unroll
        for (int kk = 0; kk < KITER; ++kk) {
            bf16x8 af = *(const bf16x8*)(Ab + (((l4 * 16 + kk * 64)) ^ aswz));
            #pragma unroll
            for (int c = 0; c < 4; ++c) {
                bf16x8 bfr = *(const bf16x8*)(Bb + c * 16 * KW + kk * 32);
                acc[c] = __builtin_amdgcn_mfma_f32_16x16x32_bf16(af, bfr, acc[c], 0, 0, 0);
            }
        }
        // C/D: col = lane&15 -> o, row = (lane>>4)*4 + reg -> t (4 consecutive)
        const int tb = t0 + l4 * 4;
        #pragma unroll
        for (int c = 0; c < 4; ++c) {
            int o = c * 16 + l15;
            float* op = out + ((size_t)(n * O_DIM + o) * J_DIM + j) * T_DIM + tb;
            *(f32x4*)op = acc[c];
        }
    }
}

extern "C" void kernel_launch(void* const* d_in, const int* in_sizes, int n_in,
                              void* d_out, int out_size, void* d_ws, size_t ws_size,
                              hipStream_t stream) {
    const float* x = (const float*)d_in[0];
    const float* W = (const float*)d_in[1];
    const float* b = (const float*)d_in[2];
    float* out = (float*)d_out;
    unsigned short* Wf = (unsigned short*)d_ws;    // 64*320*2 = 40,960 B

    wprep<<<(O_DIM * (KW / 8) + 255) / 256, 256, 0, stream>>>(W, Wf);
    sig_mfma<<<N_DIM * J_DIM * 2, 256, 0, stream>>>(x, Wf, b, out);
}

// Round 4
// 60.372 us; speedup vs baseline: 1.4281x; 1.4281x over previous
//
#include <hip/hip_runtime.h>

#define J_DIM 25
#define T_DIM 120
#define O_DIM 64
#define KPAD  328        // bf16 per ys row; 656 B = 164 dwords == 4 mod 32 -> 2-way banks
#define TB    30         // t-rows per block
#define WROWS 34         // staged window rows (t_local + w <= 33)
#define XPAD  20         // xs row pad (floats): 80 B rows, 16-aligned

typedef __attribute__((ext_vector_type(8))) short bf16x8;
typedef __attribute__((ext_vector_type(4))) float f32x4;

__device__ __forceinline__ unsigned f2bf(float f) {
    union { float f; unsigned u; } v; v.f = f;
    return (v.u + 0x7FFFu + ((v.u >> 16) & 1u)) >> 16;
}
__device__ __forceinline__ unsigned pk2(float lo, float hi) {
    return f2bf(lo) | (f2bf(hi) << 16);
}

// ---- W (306x64 f32) -> Wf[o][k], k = 18a + b; b<17: 0.5*W2[a,b]; b==17: W1[a] ----
__global__ void wprep(const float* __restrict__ W, unsigned short* __restrict__ Wf) {
    int i = blockIdx.x * 256 + threadIdx.x;
    if (i >= O_DIM * KPAD) return;
    int o = i / KPAD, k = i % KPAD;
    int a = k / 18, b = k % 18;
    float v = 0.0f;
    if (k < 306) v = (b == 17) ? W[a * O_DIM + o] : 0.5f * W[(17 + 17 * a + b) * O_DIM + o];
    Wf[o * KPAD + k] = (unsigned short)f2bf(v);
}

// ---- main: block = (n, j, 30-t quarter) ----
__global__ __launch_bounds__(256, 4) void sig_mfma(
    const float* __restrict__ x, const unsigned short* __restrict__ Wf,
    const float* __restrict__ bias, float* __restrict__ out)
{
    __shared__ float xs[WROWS][XPAD];            // 2720 B
    __shared__ unsigned short ys[TB * KPAD];     // 19680 B

    const int tid = threadIdx.x;
    const int bid = blockIdx.x;
    const int q4 = bid & 3;
    const int j  = (bid >> 2) % J_DIM;
    const int n  = bid / (4 * J_DIM);
    const int t0 = q4 * TB;

    // ---- stage xs[i][c] = x[n,c,j,clamp(t0-2+i)]  (pre-clamped, window-indexed) ----
    const float* xbase = x + ((size_t)(n * 16) * J_DIM + j) * T_DIM;
    for (int idx = tid; idx < 16 * WROWS; idx += 256) {
        int i = idx % WROWS, c = idx / WROWS;
        int st = min(max(t0 - 2 + i, 0), T_DIM - 1);
        xs[i][c] = xbase[(size_t)c * J_DIM * T_DIM + st];
    }
    // zero k = 304..327 pad region (bytes 608..655 per row; 608-611 re-written in phase 1)
    if (tid < TB * 3) {
        int r = tid / 3, p = tid % 3;
        *(uint4*)((char*)ys + r * 656 + 608 + p * 16) = uint4{0, 0, 0, 0};
    }
    __syncthreads();

    // ---- phase 1: thread (t_local, q) -> S2 rows a = 2q, 2q+1 (+ row 16 by q==0) ----
    {
        const int wave = tid >> 6, lane = tid & 63;
        const int tl8 = lane & 7, q = lane >> 3;
        const int tloc = wave * 8 + tl8;
        if (tloc < TB) {
            const int t = t0 + tloc;
            const int start = max(t - 2, 0), end = min(t + 3, T_DIM);
            const float inv = 1.0f / (float)(end - start - 1);
            float ptv[5];
            #pragma unroll
            for (int w = 0; w < 5; ++w) {
                int pcw = min(max(t - 2 + w, 0), T_DIM - 1);
                ptv[w] = (float)(pcw - start) * inv;
            }
            float pa0[5], pa1[5];
            #pragma unroll
            for (int w = 0; w < 5; ++w) {
                float2 pr = *(const float2*)&xs[tloc + w][2 * q];
                pa0[w] = pr.x; pa1[w] = pr.y;
            }
            float sa0[5], sa1[5], sat[5];        // p_{w-1}+p_w  (x2 folded into Wf)
            sa0[0] = pa0[0]; sa1[0] = pa1[0]; sat[0] = ptv[0];
            #pragma unroll
            for (int w = 1; w < 5; ++w) {
                sa0[w] = pa0[w - 1] + pa0[w];
                sa1[w] = pa1[w - 1] + pa1[w];
                sat[w] = ptv[w - 1] + ptv[w];
            }
            unsigned u0[9], u1[9], ut[9];
            float accp0 = 0, accp1 = 0, accpt = 0;
            #pragma unroll
            for (int hb = 0; hb < 2; ++hb) {
                float4 xw[5][2];
                #pragma unroll
                for (int w = 0; w < 5; ++w) {
                    const float* rw = &xs[tloc + w][0];
                    xw[w][0] = *(const float4*)(rw + 8 * hb);
                    xw[w][1] = *(const float4*)(rw + 8 * hb + 4);
                }
                #pragma unroll
                for (int b8 = 0; b8 < 8; ++b8) {
                    float pb[5];
                    #pragma unroll
                    for (int w = 0; w < 5; ++w) {
                        float4 v = xw[w][b8 >> 2];
                        pb[w] = ((b8 & 3) == 0) ? v.x : ((b8 & 3) == 1) ? v.y
                              : ((b8 & 3) == 2) ? v.z : v.w;
                    }
                    float dv[5];
                    dv[0] = pb[0];
                    #pragma unroll
                    for (int w = 1; w < 5; ++w) dv[w] = pb[w] - pb[w - 1];
                    float a0 = 0, a1 = 0, at = 0;
                    #pragma unroll
                    for (int w = 0; w < 5; ++w) {
                        a0 = fmaf(sa0[w], dv[w], a0);
                        a1 = fmaf(sa1[w], dv[w], a1);
                        at = fmaf(sat[w], dv[w], at);
                    }
                    const int b = hb * 8 + b8;
                    if (b & 1) {
                        const int m = b >> 1;
                        u0[m] = pk2(accp0, a0);
                        u1[m] = pk2(accp1, a1);
                        ut[m] = pk2(accpt, at);
                    } else { accp0 = a0; accp1 = a1; accpt = at; }
                }
            }
            {   // b = 16 (time column) + S1 slot
                float dv[5];
                dv[0] = ptv[0];
                #pragma unroll
                for (int w = 1; w < 5; ++w) dv[w] = ptv[w] - ptv[w - 1];
                float a0 = 0, a1 = 0, at = 0;
                #pragma unroll
                for (int w = 0; w < 5; ++w) {
                    a0 = fmaf(sa0[w], dv[w], a0);
                    a1 = fmaf(sa1[w], dv[w], a1);
                    at = fmaf(sat[w], dv[w], at);
                }
                u0[8] = pk2(a0, pa0[4]);
                u1[8] = pk2(a1, pa1[4]);
                ut[8] = pk2(at, ptv[4]);
            }
            // contiguous 72 B span: rows 2q, 2q+1 -> 9 x b64 (conflict-free by layout)
            char* yr = (char*)ys + tloc * 656 + 72 * q;
            *(uint2*)(yr +  0) = uint2{u0[0], u0[1]};
            *(uint2*)(yr +  8) = uint2{u0[2], u0[3]};
            *(uint2*)(yr + 16) = uint2{u0[4], u0[5]};
            *(uint2*)(yr + 24) = uint2{u0[6], u0[7]};
            *(uint2*)(yr + 32) = uint2{u0[8], u1[0]};
            *(uint2*)(yr + 40) = uint2{u1[1], u1[2]};
            *(uint2*)(yr + 48) = uint2{u1[3], u1[4]};
            *(uint2*)(yr + 56) = uint2{u1[5], u1[6]};
            *(uint2*)(yr + 64) = uint2{u1[7], u1[8]};
            if (q == 0) {                         // row a = 16 at bytes 576..611
                char* yr16 = (char*)ys + tloc * 656 + 576;
                *(uint2*)(yr16 +  0) = uint2{ut[0], ut[1]};
                *(uint2*)(yr16 +  8) = uint2{ut[2], ut[3]};
                *(uint2*)(yr16 + 16) = uint2{ut[4], ut[5]};
                *(uint2*)(yr16 + 24) = uint2{ut[6], ut[7]};
                *(unsigned*)(yr16 + 32) = ut[8];
            }
        }
    }
    __syncthreads();

    // ---- phase 2: 4 waves = (row-tile {0,14}) x (o-half) ; 16x32 out each ----
    {
        const int wave = tid >> 6, lane = tid & 63;
        const int l15 = lane & 15, l4 = lane >> 4;
        const int rt = wave & 1, ch = wave >> 1;
        const int t0w = rt * 14;
        const int o01 = ch * 2;
        f32x4 acc[2];
        #pragma unroll
        for (int cc = 0; cc < 2; ++cc) {
            float bv = bias[(o01 + cc) * 16 + l15];
            acc[cc] = f32x4{bv, bv, bv, bv};
        }
        const char* Ab = (const char*)ys + (t0w + l15) * 656 + l4 * 16;
        const unsigned short* Bb = Wf + (size_t)l15 * KPAD + l4 * 8;
        #pragma unroll
        for (int kk = 0; kk < 10; ++kk) {
            bf16x8 af = *(const bf16x8*)(Ab + kk * 64);
            #pragma unroll
            for (int cc = 0; cc < 2; ++cc) {
                bf16x8 bfr = *(const bf16x8*)(Bb + (size_t)((o01 + cc) * 16) * KPAD + kk * 32);
                acc[cc] = __builtin_amdgcn_mfma_f32_16x16x32_bf16(af, bfr, acc[cc], 0, 0, 0);
            }
        }
        const int tg = t0 + t0w + l4 * 4;
        #pragma unroll
        for (int cc = 0; cc < 2; ++cc) {
            int o = (o01 + cc) * 16 + l15;
            *(f32x4*)(out + ((size_t)(n * O_DIM + o) * J_DIM + j) * T_DIM + tg) = acc[cc];
        }
    }
}

extern "C" void kernel_launch(void* const* d_in, const int* in_sizes, int n_in,
                              void* d_out, int out_size, void* d_ws, size_t ws_size,
                              hipStream_t stream) {
    const float* x = (const float*)d_in[0];
    const float* W = (const float*)d_in[1];
    const float* b = (const float*)d_in[2];
    float* out = (float*)d_out;
    unsigned short* Wf = (unsigned short*)d_ws;   // 64*328*2 = 41,984 B

    wprep<<<(O_DIM * KPAD + 255) / 256, 256, 0, stream>>>(W, Wf);
    sig_mfma<<<64 * J_DIM * 4, 256, 0, stream>>>(x, Wf, b, out);
}